// Round 11
// baseline (166.548 us; speedup 1.0000x reference)
//
#include <hip/hip_runtime.h>
#include <hip/hip_bf16.h>
#include <math.h>

#define NSEQ 26
#define NSUP 25
#define LSEQ 46
#define DJ 90
#define H1 180
#define DIN 256
#define TT 1035
#define TTP 1056     // padded to 33*32
#define DOUT 128
#define WAY 5
#define SHOT 5
#define LNB 32       // logits partial blocks per class
#define SQRT_SCALE 0.29730177875068026f   // (1/sqrt(128))^0.5, folded into K (Q and K both)

typedef __attribute__((ext_vector_type(8))) short short8;
typedef __attribute__((ext_vector_type(4))) float f32x4;

__device__ __forceinline__ ushort f2bf(float x) {
    __hip_bfloat16 h = __float2bfloat16(x);
    return *reinterpret_cast<ushort*>(&h);
}

// ---------------- kernel 1: MLP (two relu layers) + positional encoding ----------------
__global__ void mlp_pe_kernel(const float* __restrict__ ss, const float* __restrict__ qsk,
                              const float* __restrict__ w1, const float* __restrict__ b1,
                              const float* __restrict__ w2, const float* __restrict__ b2,
                              float* __restrict__ feat) {
    __shared__ float xs[DJ];
    __shared__ float hs[H1];
    int r = blockIdx.x;
    int seq = r / LSEQ, l = r % LSEQ;
    const float* x = (seq < NSUP) ? (ss + (size_t)(seq * LSEQ + l) * DJ)
                                  : (qsk + (size_t)l * DJ);
    int tid = threadIdx.x;
    if (tid < DJ) xs[tid] = x[tid];
    __syncthreads();
    if (tid < H1) {
        float a = b1[tid];
        for (int k = 0; k < DJ; ++k) a += xs[k] * w1[k * H1 + tid];
        hs[tid] = fmaxf(a, 0.f);
    }
    __syncthreads();
    int d = tid;  // 0..255
    float a = b2[d];
    for (int k = 0; k < H1; ++k) a += hs[k] * w2[k * DIN + d];
    a = fmaxf(a, 0.f);
    int p2 = d & ~1;
    float freq = expf((float)p2 * (-9.210340371976184f / 256.0f));
    float ang = (float)l * freq;
    a += ((d & 1) ? cosf(ang) : sinf(ang)) * 0.1f;
    feat[(size_t)r * DIN + d] = a;
}

// ---------------- kernel 2: per-frame half projections (factorized tuple GEMM) ----------------
__global__ void proj_kernel(const float* __restrict__ feat,
                            const float* __restrict__ kw, const float* __restrict__ vw,
                            float* __restrict__ kp1, float* __restrict__ kp2,
                            float* __restrict__ vp1, float* __restrict__ vp2) {
    __shared__ float fs[DIN];
    int r = blockIdx.x, d = threadIdx.x;  // 128 threads
    fs[d] = feat[(size_t)r * DIN + d];
    fs[d + 128] = feat[(size_t)r * DIN + d + 128];
    __syncthreads();
    float a1 = 0.f, a2 = 0.f, a3 = 0.f, a4 = 0.f;
    for (int k = 0; k < DIN; ++k) {
        float f = fs[k];
        a1 += f * kw[k * DOUT + d];
        a2 += f * kw[(k + DIN) * DOUT + d];
        a3 += f * vw[k * DOUT + d];
        a4 += f * vw[(k + DIN) * DOUT + d];
    }
    size_t o = (size_t)r * DOUT + d;
    kp1[o] = a1; kp2[o] = a2; vp1[o] = a3; vp2[o] = a4;
}

// ---------------- kernel 3: tuple gather + bias + LayerNorm -> Kbf(bf16, pre-scaled,
// support rows stored KEY-PERMUTED so QK^T output regs == PV B-operand slots), V(f32) ----------------
__global__ void kv_kernel(const float* __restrict__ kp1, const float* __restrict__ kp2,
                          const float* __restrict__ vp1, const float* __restrict__ vp2,
                          const float* __restrict__ kb, const float* __restrict__ vb,
                          const float* __restrict__ lg, const float* __restrict__ lb,
                          ushort* __restrict__ Kbf, float* __restrict__ V) {
    int b = blockIdx.x;
    int s = b / TT, t = b % TT;
    int i = 0, rem = t;
    while (rem >= (LSEQ - 1 - i)) { rem -= (LSEQ - 1 - i); ++i; }
    int j = i + 1 + rem;
    int d = threadIdx.x;  // 128 threads
    size_t fi = (size_t)(s * LSEQ + i) * DOUT + d;
    size_t fj = (size_t)(s * LSEQ + j) * DOUT + d;
    float kv = kp1[fi] + kp2[fj] + kb[d];
    float vv = vp1[fi] + vp2[fj] + vb[d];
    float sum = kv, sq = kv * kv;
    for (int off = 32; off >= 1; off >>= 1) {
        sum += __shfl_down(sum, off);
        sq  += __shfl_down(sq, off);
    }
    __shared__ float red[4];
    int wid = d >> 6, lane = d & 63;
    if (lane == 0) { red[wid * 2] = sum; red[wid * 2 + 1] = sq; }
    __syncthreads();
    sum = red[0] + red[2]; sq = red[1] + red[3];
    float m = sum * (1.f / DOUT);
    float var = sq * (1.f / DOUT) - m * m;
    float rs = rsqrtf(var + 1e-5f);
    float kn = ((kv - m) * rs * lg[d] + lb[d]) * SQRT_SCALE;
    // support rows: permute within 32-key tile by f^-1 so that MFMA C-row i
    // holds key f(i); query seq (s==NSUP) stays natural (it is the Q operand).
    int tk = t;
    if (s < NSUP) {
        int jq = t & 31;
        int pos = (jq & 4) ? (16 + ((jq >> 3) << 2) + (jq & 3))
                           : (((jq >> 3) << 2) + (jq & 3));
        tk = (t & ~31) | pos;
    }
    Kbf[(size_t)s * TTP * DOUT + (size_t)tk * DOUT + d] = f2bf(kn);
    V[((size_t)s * TT + t) * DOUT + d] = vv;
}

// ---------------- kernel 3b: V -> bf16 transpose  VbfT[p][d][t] (natural key order) ----------------
__global__ void vtrans_kernel(const float* __restrict__ V, ushort* __restrict__ VbfT) {
    __shared__ float tile[32][33];
    int p = blockIdx.z;
    int t0 = blockIdx.x * 32, d0 = blockIdx.y * 32;
    int tx = threadIdx.x & 31, ty = threadIdx.x >> 5;  // 256 thr: ty 0..7
    for (int i = ty; i < 32; i += 8) {
        int t = t0 + i;
        tile[i][tx] = (t < TT) ? V[((size_t)p * TT + t) * DOUT + d0 + tx] : 0.f;
    }
    __syncthreads();
    for (int i = ty; i < 32; i += 8) {
        int d = d0 + i;
        VbfT[((size_t)p * DOUT + d) * TTP + t0 + tx] = f2bf(tile[tx][i]);
    }
}

// ---------------- kernel 4: split-K MFMA flash attention, zero-exchange P ----------------
// 2-wave blocks (128 thr): 1625 blocks x 2 waves = 3250 waves -> ENTIRE grid
// resident at the 4-waves/SIMD VGPR class (m69 step: 65..128 VGPR), no tail.
// K stored key-permuted => QK^T output regs are PV B-operand slots (P in-reg).
// Fixed-max softmax. BOTH K and V fragments register-prefetched 1 tile ahead
// (L2 latency hidden under the previous tile's compute). Pad-mask only in the
// single tile containing keys >= TT (uniform branch).
__global__ __launch_bounds__(128) void attn_mfma_kernel(
        const ushort* __restrict__ Kbf, const ushort* __restrict__ VbfT,
        float* __restrict__ Obuf) {
    __shared__ float Ocomb[2][16][68];    // q rows, 64 d cols + pad
    __shared__ float lstats[16][2];       // [q][wave]

    // bijective XCD-chunk swizzle (nwg=1625, nwg%8=1)
    const int nwg = 65 * NSUP;
    int orig = blockIdx.x;
    int cq = nwg >> 3, cr = nwg & 7;           // 203, 1
    int xcd = orig & 7, sub = orig >> 3;
    int wg = (xcd < cr ? xcd * (cq + 1) : cr * (cq + 1) + (xcd - cr) * cq) + sub;
    int p = wg / 65;                            // support pair 0..24
    int q0 = (wg % 65) * 16;

    int tid = threadIdx.x;
    int wid = tid >> 6;                         // 0..1
    int lane = tid & 63;
    int g = lane >> 4, r16 = lane & 15;

    const ushort* Kq = Kbf + (size_t)NSUP * TTP * DOUT;   // query rows (natural order)
    short8 qf[4];
    int qrow = q0 + r16;
    #pragma unroll
    for (int kc = 0; kc < 4; ++kc)
        qf[kc] = *(const short8*)(Kq + (size_t)qrow * DOUT + kc * 32 + g * 8);

    const ushort* Ks = Kbf + (size_t)p * TTP * DOUT;
    const ushort* Vt = VbfT + (size_t)p * DOUT * TTP;

    f32x4 o[8];
    #pragma unroll
    for (int i = 0; i < 8; ++i) o[i] = (f32x4){0.f, 0.f, 0.f, 0.f};
    float lacc = 0.f;   // per-lane partial denom for q=r16

    // key-tile range: wave0 -> tiles 0..16, wave1 -> 17..32
    int jt0 = wid * 17;
    int ntl = 17 - wid;

    // preload K and V fragments for first tile
    short8 kf[8], vf[8];
    {
        int k0 = jt0 * 32;
        #pragma unroll
        for (int kc = 0; kc < 4; ++kc) {
            kf[2 * kc]     = *(const short8*)(Ks + (size_t)(k0 + r16) * DOUT + kc * 32 + g * 8);
            kf[2 * kc + 1] = *(const short8*)(Ks + (size_t)(k0 + 16 + r16) * DOUT + kc * 32 + g * 8);
        }
        #pragma unroll
        for (int db = 0; db < 8; ++db)
            vf[db] = *(const short8*)(Vt + (size_t)(db * 16 + r16) * TTP + k0 + g * 8);
    }

    for (int jj = 0; jj < ntl; ++jj) {
        int k0 = (jt0 + jj) * 32;
        int nk0 = (jj + 1 < ntl) ? k0 + 32 : jt0 * 32;
        f32x4 s0 = (f32x4){0.f, 0.f, 0.f, 0.f};
        f32x4 s1 = (f32x4){0.f, 0.f, 0.f, 0.f};
        __builtin_amdgcn_s_setprio(1);
        #pragma unroll
        for (int kc = 0; kc < 4; ++kc) {
            s0 = __builtin_amdgcn_mfma_f32_16x16x32_bf16(kf[2 * kc],     qf[kc], s0, 0, 0, 0);
            s1 = __builtin_amdgcn_mfma_f32_16x16x32_bf16(kf[2 * kc + 1], qf[kc], s1, 0, 0, 0);
        }
        __builtin_amdgcn_s_setprio(0);
        // refill kf for the NEXT tile (in flight across softmax+PV)
        #pragma unroll
        for (int kc = 0; kc < 4; ++kc) {
            kf[2 * kc]     = *(const short8*)(Ks + (size_t)(nk0 + r16) * DOUT + kc * 32 + g * 8);
            kf[2 * kc + 1] = *(const short8*)(Ks + (size_t)(nk0 + 16 + r16) * DOUT + kc * 32 + g * 8);
        }
        // fixed-max softmax; s0[r] is key 8g+r, s1[r] is key 8g+4+r (permuted K)
        float a[8];
        if (k0 + 32 > TT) {   // uniform: only the tile holding padded keys
            #pragma unroll
            for (int r = 0; r < 4; ++r) {
                a[r]     = (k0 + 8 * g + r < TT)     ? __expf(s0[r]) : 0.f;
                a[4 + r] = (k0 + 8 * g + 4 + r < TT) ? __expf(s1[r]) : 0.f;
            }
        } else {
            #pragma unroll
            for (int r = 0; r < 4; ++r) { a[r] = __expf(s0[r]); a[4 + r] = __expf(s1[r]); }
        }
        lacc += ((a[0] + a[1]) + (a[2] + a[3])) + ((a[4] + a[5]) + (a[6] + a[7]));
        short8 pa;
        #pragma unroll
        for (int i2 = 0; i2 < 8; ++i2) pa[i2] = (short)f2bf(a[i2]);
        // PV: O^T[d][q] = mfma(A=V^T rows d, B=P cols q); vf was prefetched
        __builtin_amdgcn_s_setprio(1);
        #pragma unroll
        for (int db = 0; db < 8; ++db)
            o[db] = __builtin_amdgcn_mfma_f32_16x16x32_bf16(vf[db], pa, o[db], 0, 0, 0);
        __builtin_amdgcn_s_setprio(0);
        // refill vf for the NEXT tile
        #pragma unroll
        for (int db = 0; db < 8; ++db)
            vf[db] = *(const short8*)(Vt + (size_t)(db * 16 + r16) * TTP + nk0 + g * 8);
    }

    // ---- epilogue: per-lane denom (q=r16), plain-sum cross-wave combine ----
    lacc += __shfl_xor(lacc, 16);
    lacc += __shfl_xor(lacc, 32);          // all g now hold full wave-l for q=r16
    if (g == 0) lstats[r16][wid] = lacc;
    __syncthreads();
    float invL = 1.f / (lstats[r16][0] + lstats[r16][1]);   // per-lane, q=r16
    #pragma unroll
    for (int rd = 0; rd < 2; ++rd) {
        __syncthreads();   // previous round's reads (and lstats reads) complete
        #pragma unroll
        for (int dh = 0; dh < 4; ++dh) {
            int db = rd * 4 + dh;
            float4 w4 = make_float4(o[db][0] * invL, o[db][1] * invL,
                                    o[db][2] * invL, o[db][3] * invL);
            *(float4*)&Ocomb[wid][r16][dh * 16 + 4 * g] = w4;
        }
        __syncthreads();
        #pragma unroll
        for (int e = tid; e < 16 * 64; e += 128) {
            int q = e >> 6, dd = e & 63;
            int qg = q0 + q;
            if (qg < TT) {
                float s = Ocomb[0][q][dd] + Ocomb[1][q][dd];
                Obuf[((size_t)p * TT + qg) * DOUT + rd * 64 + dd] = s;
            }
        }
    }
}

// ---------------- kernel 5: proto = mean over shots ----------------
__global__ void proto_kernel(const float* __restrict__ Obuf, float* __restrict__ proto) {
    int c = blockIdx.y;
    int idx = blockIdx.x * 256 + threadIdx.x;
    if (idx >= TT * DOUT) return;
    float a = 0.f;
    #pragma unroll
    for (int s = 0; s < SHOT; ++s)
        a += Obuf[((size_t)(c * SHOT + s) * TT) * DOUT + idx];
    proto[(size_t)c * TT * DOUT + idx] = a * 0.2f;
}

// ---------------- kernel 6a: logits partial sums (parallel) ----------------
__global__ __launch_bounds__(256) void logits_partial_kernel(
        const float* __restrict__ V, const float* __restrict__ proto,
        float* __restrict__ partial) {
    int c = blockIdx.y, tid = threadIdx.x;
    const float4* qv = (const float4*)(V + (size_t)NSUP * TT * DOUT);
    const float4* pr = (const float4*)(proto + (size_t)c * TT * DOUT);
    float sum = 0.f;
    const int n4 = TT * DOUT / 4;   // 33120
    for (int i = blockIdx.x * 256 + tid; i < n4; i += LNB * 256) {
        float4 q = qv[i], p = pr[i];
        float dx = q.x - p.x, dy = q.y - p.y, dz = q.z - p.z, dw = q.w - p.w;
        sum += dx * dx + dy * dy + dz * dz + dw * dw;
    }
    for (int off = 32; off >= 1; off >>= 1) sum += __shfl_down(sum, off);
    __shared__ float red[4];
    int w = tid >> 6, lane = tid & 63;
    if (lane == 0) red[w] = sum;
    __syncthreads();
    if (tid == 0) partial[c * LNB + blockIdx.x] = red[0] + red[1] + red[2] + red[3];
}

// ---------------- kernel 6b: logits finalize ----------------
__global__ void logits_final_kernel(const float* __restrict__ partial, float* __restrict__ out) {
    int c = threadIdx.x;
    if (c < WAY) {
        float s = 0.f;
        #pragma unroll
        for (int b = 0; b < LNB; ++b) s += partial[c * LNB + b];
        out[c] = -s / (float)TT;
    }
}

// ---------------- kernel 7: argmax + is_true = exp(qv - proto[best]) ----------------
__global__ void istrue_kernel(const float* __restrict__ V, const float* __restrict__ proto,
                              float* out) {
    float l0 = out[0];
    int best = 0;
    for (int cc = 1; cc < WAY; ++cc) {
        float lc = out[cc];
        if (lc > l0) { l0 = lc; best = cc; }
    }
    const float* qv = V + (size_t)NSUP * TT * DOUT;
    const float* pr = proto + (size_t)best * TT * DOUT;
    int idx = blockIdx.x * 256 + threadIdx.x;
    if (idx < TT * DOUT) out[5 + idx] = expf(qv[idx] - pr[idx]);
}

extern "C" void kernel_launch(void* const* d_in, const int* in_sizes, int n_in,
                              void* d_out, int out_size, void* d_ws, size_t ws_size,
                              hipStream_t stream) {
    const float* ss  = (const float*)d_in[0];
    const float* qsk = (const float*)d_in[1];
    // d_in[2] = ss_labels (sorted balanced; reduces to a reshape)
    const float* w1 = (const float*)d_in[3];
    const float* b1 = (const float*)d_in[4];
    const float* w2 = (const float*)d_in[5];
    const float* b2 = (const float*)d_in[6];
    const float* kw = (const float*)d_in[7];
    const float* kb = (const float*)d_in[8];
    const float* vw = (const float*)d_in[9];
    const float* vb = (const float*)d_in[10];
    const float* lg = (const float*)d_in[11];
    const float* lb = (const float*)d_in[12];
    float* out = (float*)d_out;

    float* w = (float*)d_ws;
    float* feat = w;                                   // 1196*256 f32
    float* kp1  = feat + 1196 * 256;                   // 1196*128 f32 each
    float* kp2  = kp1 + 1196 * 128;
    float* vp1  = kp2 + 1196 * 128;
    float* vp2  = vp1 + 1196 * 128;
    float* Vb   = vp2 + 1196 * 128;                    // 26*1035*128 f32
    float* Obuf = Vb + (size_t)NSEQ * TT * DOUT;       // 25*1035*128 f32
    float* proto = Obuf + (size_t)NSUP * TT * DOUT;    // 5*1035*128 f32
    float* partial = proto + (size_t)WAY * TT * DOUT;  // WAY*LNB f32
    ushort* Kbf = (ushort*)(partial + WAY * LNB);      // 26*1056*128 u16
    ushort* VbfT = Kbf + (size_t)NSEQ * TTP * DOUT;    // 25*128*1056 u16
    // total ~47 MB

    hipLaunchKernelGGL(mlp_pe_kernel, dim3(NSEQ * LSEQ), dim3(256), 0, stream,
                       ss, qsk, w1, b1, w2, b2, feat);
    hipLaunchKernelGGL(proj_kernel, dim3(NSEQ * LSEQ), dim3(128), 0, stream,
                       feat, kw, vw, kp1, kp2, vp1, vp2);
    hipLaunchKernelGGL(kv_kernel, dim3(NSEQ * TT), dim3(128), 0, stream,
                       kp1, kp2, vp1, vp2, kb, vb, lg, lb, Kbf, Vb);
    hipLaunchKernelGGL(vtrans_kernel, dim3(33, 4, NSUP), dim3(256), 0, stream,
                       Vb, VbfT);
    hipLaunchKernelGGL(attn_mfma_kernel, dim3(65 * NSUP), dim3(128), 0, stream,
                       Kbf, VbfT, Obuf);
    hipLaunchKernelGGL(proto_kernel, dim3((TT * DOUT + 255) / 256, WAY), dim3(256), 0, stream,
                       Obuf, proto);
    hipLaunchKernelGGL(logits_partial_kernel, dim3(LNB, WAY), dim3(256), 0, stream,
                       Vb, proto, partial);
    hipLaunchKernelGGL(logits_final_kernel, dim3(1), dim3(64), 0, stream, partial, out);
    hipLaunchKernelGGL(istrue_kernel, dim3((TT * DOUT + 255) / 256), dim3(256), 0, stream,
                       Vb, proto, out);
}

// Round 12
// 99.705 us; speedup vs baseline: 1.6704x; 1.6704x over previous
//
#include <hip/hip_runtime.h>
#include <hip/hip_bf16.h>
#include <math.h>

#define NSEQ 26
#define NSUP 25
#define LSEQ 46
#define DJ 90
#define H1 180
#define DIN 256
#define TT 1035
#define TTP 1056     // 33*32 keys padded
#define DOUT 128
#define WAY 5
#define SHOT 5
#define LNB 32
#define SQRT_SCALE 0.29730177875068026f   // (1/sqrt(128))^0.5 folded into K (Q and K both)

typedef __attribute__((ext_vector_type(8))) short short8;
typedef __attribute__((ext_vector_type(4))) float f32x4;

__device__ __forceinline__ ushort f2bf(float x) {
    __hip_bfloat16 h = __float2bfloat16(x);
    return *reinterpret_cast<ushort*>(&h);
}

// ---------------- kernel 1: MLP (two relu layers) + positional encoding ----------------
__global__ void mlp_pe_kernel(const float* __restrict__ ss, const float* __restrict__ qsk,
                              const float* __restrict__ w1, const float* __restrict__ b1,
                              const float* __restrict__ w2, const float* __restrict__ b2,
                              float* __restrict__ feat) {
    __shared__ float xs[DJ];
    __shared__ float hs[H1];
    int r = blockIdx.x;
    int seq = r / LSEQ, l = r % LSEQ;
    const float* x = (seq < NSUP) ? (ss + (size_t)(seq * LSEQ + l) * DJ)
                                  : (qsk + (size_t)l * DJ);
    int tid = threadIdx.x;
    if (tid < DJ) xs[tid] = x[tid];
    __syncthreads();
    if (tid < H1) {
        float a = b1[tid];
        for (int k = 0; k < DJ; ++k) a += xs[k] * w1[k * H1 + tid];
        hs[tid] = fmaxf(a, 0.f);
    }
    __syncthreads();
    int d = tid;  // 0..255
    float a = b2[d];
    for (int k = 0; k < H1; ++k) a += hs[k] * w2[k * DIN + d];
    a = fmaxf(a, 0.f);
    int p2 = d & ~1;
    float freq = expf((float)p2 * (-9.210340371976184f / 256.0f));
    float ang = (float)l * freq;
    a += ((d & 1) ? cosf(ang) : sinf(ang)) * 0.1f;
    feat[(size_t)r * DIN + d] = a;
}

// ---------------- kernel 2: per-frame half projections (factorized tuple GEMM) ----------------
__global__ void proj_kernel(const float* __restrict__ feat,
                            const float* __restrict__ kw, const float* __restrict__ vw,
                            float* __restrict__ kp1, float* __restrict__ kp2,
                            float* __restrict__ vp1, float* __restrict__ vp2) {
    __shared__ float fs[DIN];
    int r = blockIdx.x, d = threadIdx.x;  // 128 threads
    fs[d] = feat[(size_t)r * DIN + d];
    fs[d + 128] = feat[(size_t)r * DIN + d + 128];
    __syncthreads();
    float a1 = 0.f, a2 = 0.f, a3 = 0.f, a4 = 0.f;
    for (int k = 0; k < DIN; ++k) {
        float f = fs[k];
        a1 += f * kw[k * DOUT + d];
        a2 += f * kw[(k + DIN) * DOUT + d];
        a3 += f * vw[k * DOUT + d];
        a4 += f * vw[(k + DIN) * DOUT + d];
    }
    size_t o = (size_t)r * DOUT + d;
    kp1[o] = a1; kp2[o] = a2; vp1[o] = a3; vp2[o] = a4;
}

// ---------------- kernel 3: tuple gather + bias + LayerNorm ----------------
// Writes FRAGMENT-ORDERED bf16 buffers (16B chunks in exact lane-consumption
// order): Kbf2[p][kt][512 chunks][8], Vbf2 (= V^T frags) same, Qbf[qt][256][8].
// Support keys stored with the in-tile permutation sigma so QK^T C-regs are the
// PV B-operand slots. Padded slots (t in [TT,TTP)) written as ZERO (NaN safety).
__global__ void kv_kernel(const float* __restrict__ kp1, const float* __restrict__ kp2,
                          const float* __restrict__ vp1, const float* __restrict__ vp2,
                          const float* __restrict__ kb, const float* __restrict__ vb,
                          const float* __restrict__ lg, const float* __restrict__ lb,
                          ushort* __restrict__ Qbf, ushort* __restrict__ Kbf2,
                          ushort* __restrict__ Vbf2, float* __restrict__ Vq) {
    int b = blockIdx.x;
    int s = b / TTP, t = b % TTP;
    int d = threadIdx.x;  // 128 threads
    int kc = d >> 5, gk = (d >> 3) & 3, ek = d & 7;   // K/Q chunk coords from d

    if (t >= TT) {   // zero the padded tail (uniform per block)
        if (s < NSUP) {
            int kt = t >> 5, jq = t & 31;
            int pos = (jq & 4) ? (16 + ((jq >> 3) << 2) + (jq & 3))
                               : (((jq >> 3) << 2) + (jq & 3));
            Kbf2[(((size_t)s * 33 + kt) * 512 + (size_t)(kc * 2 + (pos >> 4)) * 64 + gk * 16 + (pos & 15)) * 8 + ek] = 0;
            int db = d >> 4, r16v = d & 15, gv = (t & 31) >> 3, ev = t & 7;
            Vbf2[(((size_t)s * 33 + kt) * 512 + (size_t)db * 64 + gv * 16 + r16v) * 8 + ev] = 0;
        } else {
            int qt = t >> 4, r16 = t & 15;
            Qbf[((size_t)qt * 256 + (size_t)kc * 64 + gk * 16 + r16) * 8 + ek] = 0;
        }
        return;
    }

    int i = 0, rem = t;
    while (rem >= (LSEQ - 1 - i)) { rem -= (LSEQ - 1 - i); ++i; }
    int j = i + 1 + rem;
    size_t fi = (size_t)(s * LSEQ + i) * DOUT + d;
    size_t fj = (size_t)(s * LSEQ + j) * DOUT + d;
    float kv = kp1[fi] + kp2[fj] + kb[d];
    float vv = vp1[fi] + vp2[fj] + vb[d];
    float sum = kv, sq = kv * kv;
    for (int off = 32; off >= 1; off >>= 1) {
        sum += __shfl_down(sum, off);
        sq  += __shfl_down(sq, off);
    }
    __shared__ float red[4];
    int wid = d >> 6, lane = d & 63;
    if (lane == 0) { red[wid * 2] = sum; red[wid * 2 + 1] = sq; }
    __syncthreads();
    sum = red[0] + red[2]; sq = red[1] + red[3];
    float m = sum * (1.f / DOUT);
    float var = sq * (1.f / DOUT) - m * m;
    float rs = rsqrtf(var + 1e-5f);
    float kn = ((kv - m) * rs * lg[d] + lb[d]) * SQRT_SCALE;

    if (s < NSUP) {
        int kt = t >> 5, jq = t & 31;
        int pos = (jq & 4) ? (16 + ((jq >> 3) << 2) + (jq & 3))
                           : (((jq >> 3) << 2) + (jq & 3));
        Kbf2[(((size_t)s * 33 + kt) * 512 + (size_t)(kc * 2 + (pos >> 4)) * 64 + gk * 16 + (pos & 15)) * 8 + ek] = f2bf(kn);
        int db = d >> 4, r16v = d & 15, gv = (t & 31) >> 3, ev = t & 7;
        Vbf2[(((size_t)s * 33 + kt) * 512 + (size_t)db * 64 + gv * 16 + r16v) * 8 + ev] = f2bf(vv);
    } else {
        int qt = t >> 4, r16 = t & 15;
        Qbf[((size_t)qt * 256 + (size_t)kc * 64 + gk * 16 + r16) * 8 + ek] = f2bf(kn);
        Vq[(size_t)t * DOUT + d] = vv;   // query V kept f32 for logits/istrue
    }
}

// ---------------- kernel 4: MFMA flash attention, shared-staging 4-wave blocks ----------------
// Block = 4 waves = 4 q-tiles (64 q rows) of one pair; all iterate the 33
// key-tiles together. Per tile: K (8KB) + V^T (8KB) staged once into LDS by
// the 4 waves cooperatively (linear coalesced copy, fragment-ordered), then
// each wave ds_read_b128's its fragments conflict-free. 4x fewer L2
// requests/bytes than per-wave register loads. P never leaves registers
// (permuted-K trick); fixed-max softmax; no split-K combine.
__global__ __launch_bounds__(256) void attn_mfma_kernel(
        const ushort* __restrict__ Qbf, const ushort* __restrict__ Kbf2,
        const ushort* __restrict__ Vbf2, float* __restrict__ Obuf) {
    __shared__ __align__(16) ushort Kl[2][4096];
    __shared__ __align__(16) ushort Vl[2][4096];

    // bijective XCD-chunk swizzle (nwg=425, nwg%8=1)
    const int nwg = 17 * NSUP;
    int orig = blockIdx.x;
    int cq = nwg >> 3, cr = nwg & 7;           // 53, 1
    int xcd = orig & 7, sub = orig >> 3;
    int wg = (xcd < cr ? xcd * (cq + 1) : cr * (cq + 1) + (xcd - cr) * cq) + sub;
    int p = wg / 17;

    int tid = threadIdx.x, wid = tid >> 6, lane = tid & 63;
    int g = lane >> 4, r16 = lane & 15;
    int qt = (wg % 17) * 4 + wid;              // q-tile 0..67 (>=65: discarded)

    short8 qf[4];
    const ushort* Qb = Qbf + (size_t)qt * 2048;
    #pragma unroll
    for (int kc = 0; kc < 4; ++kc)
        qf[kc] = *(const short8*)(Qb + (kc * 64 + lane) * 8);

    // staging: wave0 K[0:2048), wave1 K[2048:4096), wave2 V[0:2048), wave3 V[2048:)
    const ushort* gsrc = ((wid < 2) ? Kbf2 : Vbf2) + (size_t)p * 33 * 4096 + (size_t)(wid & 1) * 2048;
    ushort* ld0 = ((wid < 2) ? &Kl[0][0] : &Vl[0][0]) + (wid & 1) * 2048;
    ushort* ld1 = ((wid < 2) ? &Kl[1][0] : &Vl[1][0]) + (wid & 1) * 2048;

    f32x4 o[8];
    #pragma unroll
    for (int i = 0; i < 8; ++i) o[i] = (f32x4){0.f, 0.f, 0.f, 0.f};
    float lacc = 0.f;

    short8 st0, st1, st2, st3;
    {   // prologue: stage tile 0
        st0 = *(const short8*)(gsrc + lane * 8);
        st1 = *(const short8*)(gsrc + 512 + lane * 8);
        st2 = *(const short8*)(gsrc + 1024 + lane * 8);
        st3 = *(const short8*)(gsrc + 1536 + lane * 8);
        *(short8*)(ld0 + lane * 8) = st0;
        *(short8*)(ld0 + 512 + lane * 8) = st1;
        *(short8*)(ld0 + 1024 + lane * 8) = st2;
        *(short8*)(ld0 + 1536 + lane * 8) = st3;
        __syncthreads();
    }

    for (int jj = 0; jj < 33; ++jj) {
        const ushort* Kc = &Kl[jj & 1][0];
        const ushort* Vc = &Vl[jj & 1][0];
        if (jj + 1 < 33) {   // issue next-tile loads early (hide under compute)
            const ushort* s = gsrc + (size_t)(jj + 1) * 4096;
            st0 = *(const short8*)(s + lane * 8);
            st1 = *(const short8*)(s + 512 + lane * 8);
            st2 = *(const short8*)(s + 1024 + lane * 8);
            st3 = *(const short8*)(s + 1536 + lane * 8);
        }
        f32x4 s0 = (f32x4){0.f, 0.f, 0.f, 0.f};
        f32x4 s1 = (f32x4){0.f, 0.f, 0.f, 0.f};
        __builtin_amdgcn_s_setprio(1);
        #pragma unroll
        for (int kc = 0; kc < 4; ++kc) {
            short8 kf0 = *(const short8*)(Kc + ((kc * 2 + 0) * 64 + lane) * 8);
            short8 kf1 = *(const short8*)(Kc + ((kc * 2 + 1) * 64 + lane) * 8);
            s0 = __builtin_amdgcn_mfma_f32_16x16x32_bf16(kf0, qf[kc], s0, 0, 0, 0);
            s1 = __builtin_amdgcn_mfma_f32_16x16x32_bf16(kf1, qf[kc], s1, 0, 0, 0);
        }
        __builtin_amdgcn_s_setprio(0);
        int k0 = jj * 32;
        float a[8];
        if (k0 + 32 > TT) {   // only the final tile
            #pragma unroll
            for (int r = 0; r < 4; ++r) {
                a[r]     = (k0 + 8 * g + r < TT)     ? __expf(s0[r]) : 0.f;
                a[4 + r] = (k0 + 8 * g + 4 + r < TT) ? __expf(s1[r]) : 0.f;
            }
        } else {
            #pragma unroll
            for (int r = 0; r < 4; ++r) { a[r] = __expf(s0[r]); a[4 + r] = __expf(s1[r]); }
        }
        lacc += ((a[0] + a[1]) + (a[2] + a[3])) + ((a[4] + a[5]) + (a[6] + a[7]));
        short8 pa;
        #pragma unroll
        for (int e = 0; e < 8; ++e) pa[e] = (short)f2bf(a[e]);
        __builtin_amdgcn_s_setprio(1);
        #pragma unroll
        for (int db = 0; db < 8; ++db) {
            short8 vf = *(const short8*)(Vc + (db * 64 + lane) * 8);
            o[db] = __builtin_amdgcn_mfma_f32_16x16x32_bf16(vf, pa, o[db], 0, 0, 0);
        }
        __builtin_amdgcn_s_setprio(0);
        __syncthreads();                 // all reads of buf[cur] done
        if (jj + 1 < 33) {
            ushort* dst = ((jj + 1) & 1) ? ld1 : ld0;
            *(short8*)(dst + lane * 8) = st0;
            *(short8*)(dst + 512 + lane * 8) = st1;
            *(short8*)(dst + 1024 + lane * 8) = st2;
            *(short8*)(dst + 1536 + lane * 8) = st3;
            __syncthreads();             // next tile visible
        }
    }

    // epilogue: per-lane denom (q=r16), direct store (no cross-wave combine)
    lacc += __shfl_xor(lacc, 16);
    lacc += __shfl_xor(lacc, 32);
    float invL = 1.f / lacc;
    int qrow = qt * 16 + r16;
    if (qrow < TT) {
        float* po = Obuf + ((size_t)p * TT + qrow) * DOUT;
        #pragma unroll
        for (int db = 0; db < 8; ++db) {
            float4 w4 = make_float4(o[db][0] * invL, o[db][1] * invL,
                                    o[db][2] * invL, o[db][3] * invL);
            *(float4*)&po[db * 16 + g * 4] = w4;
        }
    }
}

// ---------------- kernel 5: proto = mean over shots ----------------
__global__ void proto_kernel(const float* __restrict__ Obuf, float* __restrict__ proto) {
    int c = blockIdx.y;
    int idx = blockIdx.x * 256 + threadIdx.x;
    if (idx >= TT * DOUT) return;
    float a = 0.f;
    #pragma unroll
    for (int s = 0; s < SHOT; ++s)
        a += Obuf[((size_t)(c * SHOT + s) * TT) * DOUT + idx];
    proto[(size_t)c * TT * DOUT + idx] = a * 0.2f;
}

// ---------------- kernel 6a: logits partial sums ----------------
__global__ __launch_bounds__(256) void logits_partial_kernel(
        const float* __restrict__ Vq, const float* __restrict__ proto,
        float* __restrict__ partial) {
    int c = blockIdx.y, tid = threadIdx.x;
    const float4* qv = (const float4*)Vq;
    const float4* pr = (const float4*)(proto + (size_t)c * TT * DOUT);
    float sum = 0.f;
    const int n4 = TT * DOUT / 4;
    for (int i = blockIdx.x * 256 + tid; i < n4; i += LNB * 256) {
        float4 q = qv[i], p = pr[i];
        float dx = q.x - p.x, dy = q.y - p.y, dz = q.z - p.z, dw = q.w - p.w;
        sum += dx * dx + dy * dy + dz * dz + dw * dw;
    }
    for (int off = 32; off >= 1; off >>= 1) sum += __shfl_down(sum, off);
    __shared__ float red[4];
    int w = tid >> 6, lane = tid & 63;
    if (lane == 0) red[w] = sum;
    __syncthreads();
    if (tid == 0) partial[c * LNB + blockIdx.x] = red[0] + red[1] + red[2] + red[3];
}

// ---------------- kernel 6b: logits finalize ----------------
__global__ void logits_final_kernel(const float* __restrict__ partial, float* __restrict__ out) {
    int c = threadIdx.x;
    if (c < WAY) {
        float s = 0.f;
        #pragma unroll
        for (int b = 0; b < LNB; ++b) s += partial[c * LNB + b];
        out[c] = -s / (float)TT;
    }
}

// ---------------- kernel 7: argmax + is_true = exp(qv - proto[best]) ----------------
__global__ void istrue_kernel(const float* __restrict__ Vq, const float* __restrict__ proto,
                              float* out) {
    float l0 = out[0];
    int best = 0;
    for (int cc = 1; cc < WAY; ++cc) {
        float lc = out[cc];
        if (lc > l0) { l0 = lc; best = cc; }
    }
    const float* pr = proto + (size_t)best * TT * DOUT;
    int idx = blockIdx.x * 256 + threadIdx.x;
    if (idx < TT * DOUT) out[5 + idx] = expf(Vq[idx] - pr[idx]);
}

extern "C" void kernel_launch(void* const* d_in, const int* in_sizes, int n_in,
                              void* d_out, int out_size, void* d_ws, size_t ws_size,
                              hipStream_t stream) {
    const float* ss  = (const float*)d_in[0];
    const float* qsk = (const float*)d_in[1];
    // d_in[2] = ss_labels (sorted balanced; reduces to a reshape)
    const float* w1 = (const float*)d_in[3];
    const float* b1 = (const float*)d_in[4];
    const float* w2 = (const float*)d_in[5];
    const float* b2 = (const float*)d_in[6];
    const float* kw = (const float*)d_in[7];
    const float* kb = (const float*)d_in[8];
    const float* vw = (const float*)d_in[9];
    const float* vb = (const float*)d_in[10];
    const float* lg = (const float*)d_in[11];
    const float* lb = (const float*)d_in[12];
    float* out = (float*)d_out;

    float* w = (float*)d_ws;
    float* feat = w;                                   // 1196*256 f32
    float* kp1  = feat + 1196 * 256;                   // 1196*128 f32 each
    float* kp2  = kp1 + 1196 * 128;
    float* vp1  = kp2 + 1196 * 128;
    float* vp2  = vp1 + 1196 * 128;
    float* Vq   = vp2 + 1196 * 128;                    // TT*128 f32 (query V)
    float* Obuf = Vq + (size_t)TT * DOUT;              // 25*TT*128 f32
    float* proto = Obuf + (size_t)NSUP * TT * DOUT;    // 5*TT*128 f32
    float* partial = proto + (size_t)WAY * TT * DOUT;  // WAY*LNB f32
    ushort* Qbf  = (ushort*)(partial + WAY * LNB);     // 68*2048 u16 (frag-order Q)
    ushort* Kbf2 = Qbf + (size_t)68 * 2048;            // 25*33*4096 u16
    ushort* Vbf2 = Kbf2 + (size_t)NSUP * 33 * 4096;    // 25*33*4096 u16
    // total ~34 MB

    hipLaunchKernelGGL(mlp_pe_kernel, dim3(NSEQ * LSEQ), dim3(256), 0, stream,
                       ss, qsk, w1, b1, w2, b2, feat);
    hipLaunchKernelGGL(proj_kernel, dim3(NSEQ * LSEQ), dim3(128), 0, stream,
                       feat, kw, vw, kp1, kp2, vp1, vp2);
    hipLaunchKernelGGL(kv_kernel, dim3(NSEQ * TTP), dim3(128), 0, stream,
                       kp1, kp2, vp1, vp2, kb, vb, lg, lb, Qbf, Kbf2, Vbf2, Vq);
    hipLaunchKernelGGL(attn_mfma_kernel, dim3(17 * NSUP), dim3(256), 0, stream,
                       Qbf, Kbf2, Vbf2, Obuf);
    hipLaunchKernelGGL(proto_kernel, dim3((TT * DOUT + 255) / 256, WAY), dim3(256), 0, stream,
                       Obuf, proto);
    hipLaunchKernelGGL(logits_partial_kernel, dim3(LNB, WAY), dim3(256), 0, stream,
                       Vq, proto, partial);
    hipLaunchKernelGGL(logits_final_kernel, dim3(1), dim3(64), 0, stream, partial, out);
    hipLaunchKernelGGL(istrue_kernel, dim3((TT * DOUT + 255) / 256), dim3(256), 0, stream,
                       Vq, proto, out);
}